// Round 1
// baseline (386.342 us; speedup 1.0000x reference)
//
#include <hip/hip_runtime.h>

#define GN 64
#define N_TOTAL (GN * GN * GN)   // 262144
#define KOFF 24

typedef float f4 __attribute__((ext_vector_type(4)));

// 24 Manhattan-radius-2 offsets, sorted by linear delta (dx*4096 + dy*64 + dz)
// ascending. List is symmetric under negation: inv(k) = 23 - k.
__device__ constexpr int DLc[KOFF] = {
    -8192, -4160, -4097, -4096, -4095, -4032,
     -128,   -65,   -64,   -63,    -2,    -1,
        1,     2,    63,    64,    65,   128,
     4032,  4095,  4096,  4097,  4160,  8192};
__device__ constexpr int DXc[KOFF] = {
    -2, -1, -1, -1, -1, -1, 0, 0, 0, 0, 0, 0,
     0,  0,  0,  0,  0,  0, 1, 1, 1, 1, 1, 2};
__device__ constexpr int DYc[KOFF] = {
     0, -1,  0,  0,  0,  1, -2, -1, -1, -1, 0, 0,
     0,  0,  1,  1,  1,  2, -1,  0,  0,  0, 1, 0};
__device__ constexpr int DZc[KOFF] = {
     0,  0, -1,  0,  1,  0,  0, -1,  0,  1, -2, -1,
     1,  2, -1,  0,  1,  0,  0, -1,  0,  1,  0,  0};

// 12 distinct (dx,dy) != (0,0) groups; a wave = one z-row, so the dz variants
// of a group are lane-shifts of the group's dz=0 element.
#define NGRP 12
__device__ constexpr int GDXc[NGRP] = {-2, -1, -1, -1,  0,  0, 0, 0,  1, 1, 1, 2};
__device__ constexpr int GDYc[NGRP] = { 0, -1,  0,  1, -2, -1, 1, 2, -1, 0, 1, 0};
__device__ constexpr int GDLc[NGRP] = {-8192, -4160, -4096, -4032, -128, -64,
                                        64, 128, 4032, 4096, 4160, 8192};
// group id per k (-1 = pure-z group, served from own o1)
__device__ constexpr int GIDc[KOFF] = {
    0, 1, 2, 2, 2, 3, 4, 5, 5, 5, -1, -1,
    -1, -1, 6, 6, 6, 7, 8, 9, 9, 9, 10, 11};

// Closed-form edge-count prefix: number of edges whose row-linear-index < j,
// evaluated at unraveled coords (x,y,z) of j.  Works for j == N via (64,0,0).
__device__ __forceinline__ int edge_prefix(int x, int y, int z) {
    int S = 0;
#pragma unroll
    for (int k = 0; k < KOFF; k++) {
        int dx = DXc[k], dy = DYc[k], dz = DZc[k];
        int x0 = max(0, -dx), x1 = min(64, 64 - dx);
        int y0 = max(0, -dy), y1 = min(64, 64 - dy);
        int z0 = max(0, -dz), z1 = min(64, 64 - dz);
        int ny = y1 - y0, nz = z1 - z0;
        int nxb = max(0, min(x, x1) - x0);
        int cnt = nxb * ny * nz;
        if (x >= x0 && x < x1) {
            cnt += max(0, min(y, y1) - y0) * nz;
            if (y >= y0 && y < y1)
                cnt += max(0, min(z, z1) - z0);
        }
        S += cnt;
    }
    return S;
}

// Deterministic re-pack of ev into INCOMING plane-major layout:
//   wIn[k*N + j] = weight of edge (j+DL[k] -> j)   (0 if that edge invalid).
// ev reads staged through LDS (coalesced segment load). Also zeroes ctr.
__global__ __launch_bounds__(256) void pack_w_kernel(
    const float* __restrict__ ev, float* __restrict__ w,
    unsigned* __restrict__ ctr) {
    __shared__ float lds[6144];
    int tid = threadIdx.x;
    int j = blockIdx.x * 256 + tid;
    if (blockIdx.x == 0) ctr[tid] = 0;   // 256 progress counters
    int z = j & 63, y = (j >> 6) & 63, x = j >> 12;

    int j0 = blockIdx.x * 256, j1 = j0 + 256;
    int Sblk = edge_prefix(j0 >> 12, (j0 >> 6) & 63, 0);
    int Send = edge_prefix(j1 >> 12, (j1 >> 6) & 63, 0);
    int Sj   = edge_prefix(x, y, z);

    int len = Send - Sblk;
    for (int i = tid; i < len; i += 256)
        lds[i] = ev[Sblk + i];
    __syncthreads();

    int rel = Sj - Sblk;
#pragma unroll
    for (int k = 0; k < KOFF; k++) {
        int nx = x + DXc[k], ny = y + DYc[k], nz = z + DZc[k];
        bool ok = ((unsigned)nx < 64u) & ((unsigned)ny < 64u) &
                  ((unsigned)nz < 64u);
        if (ok) {
            w[(23 - k) * N_TOTAL + (j + DLc[k])] = lds[rel];
            rel++;
        } else {
            w[k * N_TOTAL + j] = 0.0f;
        }
    }
}

// ------------------ persistent path (single path, plain launch) ------------------
// One thread per neuron, all T steps; w/v/out-history in VGPRs.
// NEIGHBORHOOD SYNC with the VALIDATED publish: block B only depends on
// blocks B-8..B+8 (dx=+-2 -> +-8192 j -> +-8 blocks).  Publish is the
// R8/R10/R11/R12-validated sequence (vmcnt drain -> atomicAdd RMW to own
// slot); wait polls the 17 neighbor slots with relaxed sc1 loads (R10's
// validated poll pattern).  ctr[B'] >= t  <=>  B' completed step t-1
// including all of its reads, so the out ping-pong WAR is safe by symmetry
// of the dependency window; deadlock-free by induction on (block, step).
//
// LAUNCH MECHANISM (this round's change): plain <<<256,1024>>> launch, NOT
// hipLaunchCooperativeKernel.  The sync never used grid.sync() — it only
// needs all 256 blocks co-resident.  __launch_bounds__(1024,1) caps VGPR at
// 128 so a 1024-thread block always fits a CU (16 waves = 4/SIMD); grid=256
// blocks == 256 CUs -> the dispatcher places every block immediately, for
// both direct launch and graph replay.  Cooperative launch is NOT
// stream-capturable, which made kernel_launch branch on capture state
// (graph recorded a fallback path, launch_once ran this one) -> harness
// tripwire.  One plain-launch path is capture-safe and deterministic.
__global__ __launch_bounds__(1024, 1) void sim_kernel(
    const float* __restrict__ xext,
    const float* __restrict__ wpk,
    float* __restrict__ pb0,
    float* __restrict__ pb1,
    float* __restrict__ spk,
    unsigned* __restrict__ ctr,      // one counter per block (256)
    int T) {
#pragma clang fp contract(off)
    __shared__ float sout[2][1024];
    int tid = threadIdx.x;
    int j = blockIdx.x * 1024 + tid;
    int z = j & 63, y = (j >> 6) & 63, x = j >> 12;
    int lane = tid & 63;       // == z
    int lrow = tid >> 6;       // local y-row within block [0,16)

    int bid = (int)blockIdx.x;
    int lo = max(0, bid - 8), hi = min((int)gridDim.x - 1, bid + 8);
    int ndep = hi - lo + 1;    // <= 17

    float vmask[KOFF];
#pragma unroll
    for (int k = 0; k < KOFF; k++) {
        int nx = x + DXc[k], ny = y + DYc[k], nz = z + DZc[k];
        bool ok = ((unsigned)nx < 64u) & ((unsigned)ny < 64u) &
                  ((unsigned)nz < 64u);
        vmask[k] = ok ? 1.0f : 0.0f;
    }

    float w[KOFF];
#pragma unroll
    for (int k = 0; k < KOFF; k++) w[k] = wpk[k * N_TOTAL + j];

    const float decay = expf(-1.0f / 20.0f);
    float vmem = -65.0f;
    float o1 = 0.0f;   // out_{t-1}[j]
    float o2 = 0.0f;   // out_{t-2}[j]
    float xv = __builtin_nontemporal_load(xext + j);   // slice t=0

    for (int t = 0; t < T; t++) {
        float* pb = (t & 1) ? pb0 : pb1;   // buf[(t-1)&1]
        float* pw = (t & 1) ? pb1 : pb0;   // buf[t&1]
        const float* sr = sout[1 - (t & 1)];   // LDS out_{t-1}
        float* sw = sout[t & 1];               // LDS out_t

        // ---- wait: neighborhood B-8..B+8 completed step t-1 ----
        if (t >= 1) {
            if (tid < ndep) {
                const unsigned* cp = ctr + lo + tid;
                while (__hip_atomic_load(cp, __ATOMIC_RELAXED,
                                         __HIP_MEMORY_SCOPE_AGENT) <
                       (unsigned)t)
                    __builtin_amdgcn_s_sleep(1);
            }
            __syncthreads();
        }

        float syn = 0.0f;
        if (t >= 1) {
            // group gathers: validity / in-blockness wave-uniform -> scalar
            // branches. dy-only groups mostly from LDS, dx groups from L3.
            float r[NGRP];
#pragma unroll
            for (int g = 0; g < NGRP; g++) {
                int dxg = GDXc[g], dyg = GDYc[g];
                float rv = 0.0f;
                if (dxg == 0) {
                    int ly = lrow + dyg;
                    if ((unsigned)ly < 16u) {
                        rv = sr[tid + dyg * 64];        // ds_read, same value
                    } else {
                        int ny = y + dyg;
                        if ((unsigned)ny < 64u)
                            rv = __hip_atomic_load(pb + j + GDLc[g],
                                                   __ATOMIC_RELAXED,
                                                   __HIP_MEMORY_SCOPE_AGENT);
                    }
                } else {
                    int nx = x + dxg, ny = y + dyg;
                    if (((unsigned)nx < 64u) & ((unsigned)ny < 64u))
                        rv = __hip_atomic_load(pb + j + GDLc[g],
                                               __ATOMIC_RELAXED,
                                               __HIP_MEMORY_SCOPE_AGENT);
                }
                r[g] = rv;
            }
            if (t >= 2) {
                float h1 = 0.01f * o2;
                float h2 = 0.005f * o2;
#pragma unroll
                for (int k = 0; k < KOFF; k++) {
                    int g = GIDc[k], dz = DZc[k];
                    float src = (g < 0) ? o1 : r[g];
                    float praw = (dz == 0) ? src : __shfl(src, lane + dz, 64);
                    float p = praw * vmask[k];
                    float a = h1 * p;                 // == (0.01f*o2)*p
                    float b = h2 * (1.0f - p);        // == (0.005f*o2)*(1-p)
                    float c = 1e-5f * w[k];
                    float dw = (a - b) - c;
                    w[k] = fminf(fmaxf(w[k] + dw, 0.0f), 1.0f);
                    float m = w[k] * p;   // contract(off): mul then add
                    syn = syn + m;        // k-ascending == segment_sum order
                }
            } else {   // t == 1: syn with stored w, no plasticity yet
#pragma unroll
                for (int k = 0; k < KOFF; k++) {
                    int g = GIDc[k], dz = DZc[k];
                    float src = (g < 0) ? o1 : r[g];
                    float praw = (dz == 0) ? src : __shfl(src, lane + dz, 64);
                    float p = praw * vmask[k];
                    float m = w[k] * p;
                    syn = syn + m;
                }
            }
        }
        // t == 0: prev == 0 -> syn stays 0, no buffer read (poisoned ws ok).

        float I = syn + xv;
        float vn = (vmem * decay) + (I * (1.0f - decay));
        float spike = (vn >= -50.0f) ? 1.0f : 0.0f;
        float inhib = (vn <= -70.0f) ? 1.0f : 0.0f;
        float sg = 1.0f / (1.0f + expf(-((vn - (-60.0f)) * 0.5f)));
        float o = spike + ((1.0f - spike) * (1.0f - inhib)) * sg;
        vmem = (vn * (1.0f - spike)) + (spike * (-65.0f));
        __hip_atomic_store(pw + j, o, __ATOMIC_RELAXED,
                           __HIP_MEMORY_SCOPE_AGENT);
        sw[tid] = o;   // LDS copy (write buffer != read buffer: no WAR race)
        o2 = o1;
        o1 = o;

        // ---- publish: drain data store, then bump own slot (RMW) ----
        __syncthreads();   // vmcnt(0)+lgkmcnt drain: pw & LDS visible
        if (tid == 0)
            __hip_atomic_fetch_add(ctr + bid, 1u, __ATOMIC_RELAXED,
                                   __HIP_MEMORY_SCOPE_AGENT);

        // ---- post-publish streaming (latency hides under next wait) ----
        __builtin_nontemporal_store(spike, spk + (size_t)t * N_TOTAL + j);
        int tn = (t + 1 < T) ? (t + 1) : t;
        xv = __builtin_nontemporal_load(xext + (size_t)tn * N_TOTAL + j);
    }
}

extern "C" void kernel_launch(void* const* d_in, const int* in_sizes, int n_in,
                              void* d_out, int out_size, void* d_ws, size_t ws_size,
                              hipStream_t stream) {
    const float* xext = (const float*)d_in[0];
    const float* ev   = (const float*)d_in[1];
    float* spk = (float*)d_out;

    int T = in_sizes[0] / N_TOTAL;   // 50

    // Workspace: W0 (24N) | P0 | P1 | ctr[256]  ≈ 27.3 MB.
    float* W0 = (float*)d_ws;
    float* P0 = W0 + (size_t)N_TOTAL * KOFF;
    float* P1 = P0 + N_TOTAL;
    unsigned* ctr = (unsigned*)(P1 + N_TOTAL);

    pack_w_kernel<<<N_TOTAL / 256, 256, 0, stream>>>(ev, W0, ctr);

    // Single path, capture-safe: plain launch of the persistent kernel.
    // 256 blocks x 1024 threads, __launch_bounds__(1024,1) -> VGPR<=128 ->
    // 1 block/CU guaranteed schedulable; 256 blocks on 256 CUs co-resident.
    sim_kernel<<<N_TOTAL / 1024, 1024, 0, stream>>>(xext, W0, P0, P1, spk,
                                                    ctr, T);
}

// Round 2
// 339.866 us; speedup vs baseline: 1.1367x; 1.1367x over previous
//
#include <hip/hip_runtime.h>

#define GN 64
#define N_TOTAL (GN * GN * GN)   // 262144
#define KOFF 24
#define CPAD 32                  // flag padding: 1 counter per 128 B line

typedef float f4 __attribute__((ext_vector_type(4)));

// 24 Manhattan-radius-2 offsets, sorted by linear delta (dx*4096 + dy*64 + dz)
// ascending. List is symmetric under negation: inv(k) = 23 - k.
__device__ constexpr int DLc[KOFF] = {
    -8192, -4160, -4097, -4096, -4095, -4032,
     -128,   -65,   -64,   -63,    -2,    -1,
        1,     2,    63,    64,    65,   128,
     4032,  4095,  4096,  4097,  4160,  8192};
__device__ constexpr int DXc[KOFF] = {
    -2, -1, -1, -1, -1, -1, 0, 0, 0, 0, 0, 0,
     0,  0,  0,  0,  0,  0, 1, 1, 1, 1, 1, 2};
__device__ constexpr int DYc[KOFF] = {
     0, -1,  0,  0,  0,  1, -2, -1, -1, -1, 0, 0,
     0,  0,  1,  1,  1,  2, -1,  0,  0,  0, 1, 0};
__device__ constexpr int DZc[KOFF] = {
     0,  0, -1,  0,  1,  0,  0, -1,  0,  1, -2, -1,
     1,  2, -1,  0,  1,  0,  0, -1,  0,  1,  0,  0};

// 12 distinct (dx,dy) != (0,0) groups; a wave = one z-row, so the dz variants
// of a group are lane-shifts of the group's dz=0 element.
#define NGRP 12
__device__ constexpr int GDXc[NGRP] = {-2, -1, -1, -1,  0,  0, 0, 0,  1, 1, 1, 2};
__device__ constexpr int GDYc[NGRP] = { 0, -1,  0,  1, -2, -1, 1, 2, -1, 0, 1, 0};
__device__ constexpr int GDLc[NGRP] = {-8192, -4160, -4096, -4032, -128, -64,
                                        64, 128, 4032, 4096, 4160, 8192};
// group id per k (-1 = pure-z group, served from own o1)
__device__ constexpr int GIDc[KOFF] = {
    0, 1, 2, 2, 2, 3, 4, 5, 5, 5, -1, -1,
    -1, -1, 6, 6, 6, 7, 8, 9, 9, 9, 10, 11};

// Closed-form edge-count prefix: number of edges whose row-linear-index < j,
// evaluated at unraveled coords (x,y,z) of j.  Works for j == N via (64,0,0).
__device__ __forceinline__ int edge_prefix(int x, int y, int z) {
    int S = 0;
#pragma unroll
    for (int k = 0; k < KOFF; k++) {
        int dx = DXc[k], dy = DYc[k], dz = DZc[k];
        int x0 = max(0, -dx), x1 = min(64, 64 - dx);
        int y0 = max(0, -dy), y1 = min(64, 64 - dy);
        int z0 = max(0, -dz), z1 = min(64, 64 - dz);
        int ny = y1 - y0, nz = z1 - z0;
        int nxb = max(0, min(x, x1) - x0);
        int cnt = nxb * ny * nz;
        if (x >= x0 && x < x1) {
            cnt += max(0, min(y, y1) - y0) * nz;
            if (y >= y0 && y < y1)
                cnt += max(0, min(z, z1) - z0);
        }
        S += cnt;
    }
    return S;
}

// Deterministic re-pack of ev into INCOMING plane-major layout:
//   wIn[k*N + j] = weight of edge (j+DL[k] -> j)   (0 if that edge invalid).
// ev reads staged through LDS (coalesced segment load). Also zeroes ctr
// (256 padded slots = 8192 words, zeroed by blocks 0..31).
__global__ __launch_bounds__(256) void pack_w_kernel(
    const float* __restrict__ ev, float* __restrict__ w,
    unsigned* __restrict__ ctr) {
    __shared__ float lds[6144];
    int tid = threadIdx.x;
    int j = blockIdx.x * 256 + tid;
    if (blockIdx.x < 32) ctr[blockIdx.x * 256 + tid] = 0;
    int z = j & 63, y = (j >> 6) & 63, x = j >> 12;

    int j0 = blockIdx.x * 256, j1 = j0 + 256;
    int Sblk = edge_prefix(j0 >> 12, (j0 >> 6) & 63, 0);
    int Send = edge_prefix(j1 >> 12, (j1 >> 6) & 63, 0);
    int Sj   = edge_prefix(x, y, z);

    int len = Send - Sblk;
    for (int i = tid; i < len; i += 256)
        lds[i] = ev[Sblk + i];
    __syncthreads();

    int rel = Sj - Sblk;
#pragma unroll
    for (int k = 0; k < KOFF; k++) {
        int nx = x + DXc[k], ny = y + DYc[k], nz = z + DZc[k];
        bool ok = ((unsigned)nx < 64u) & ((unsigned)ny < 64u) &
                  ((unsigned)nz < 64u);
        if (ok) {
            w[(23 - k) * N_TOTAL + (j + DLc[k])] = lds[rel];
            rel++;
        } else {
            w[k * N_TOTAL + j] = 0.0f;
        }
    }
}

// ------------------ persistent path (single path, plain launch) ------------------
// One thread per neuron, all T steps; w/v/out-history in VGPRs.
// NEIGHBORHOOD SYNC with the VALIDATED publish: block B only depends on
// blocks B-8..B+8 (dx=+-2 -> +-8192 j -> +-8 blocks).  Publish is the
// R8/R10/R11/R12-validated sequence (vmcnt drain -> atomicAdd RMW to own
// slot); wait polls the 17 neighbor slots with relaxed agent loads.
// ctr[B'] >= t  <=>  B' completed step t-1 including all of its reads, so
// the out ping-pong WAR is safe by symmetry of the dependency window;
// deadlock-free by induction on (block, step).
//
// This round: (1) flags padded to one per 128 B line (CPAD) — previously
// 256 counters shared 16 cachelines and every step put ~2000 agent-scope
// accesses on each of those lines at the MALL (256 RMWs + 17x256 pollers),
// a memory-side hot-spot that dominated the 5.2 us/step;  (2) in-block LDS
// gathers hoisted ABOVE the wait barrier (sr is stable since the step t-1
// publish barrier), so only remote gathers sit on the post-wait path.
// Float op order in the k-loop is byte-identical to the validated version.
__global__ __launch_bounds__(1024, 1) void sim_kernel(
    const float* __restrict__ xext,
    const float* __restrict__ wpk,
    float* __restrict__ pb0,
    float* __restrict__ pb1,
    float* __restrict__ spk,
    unsigned* __restrict__ ctr,      // one padded counter per block (256)
    int T) {
#pragma clang fp contract(off)
    __shared__ float sout[2][1024];
    int tid = threadIdx.x;
    int j = blockIdx.x * 1024 + tid;
    int z = j & 63, y = (j >> 6) & 63, x = j >> 12;
    int lane = tid & 63;       // == z
    int lrow = tid >> 6;       // local y-row within block [0,16)

    int bid = (int)blockIdx.x;
    int lo = max(0, bid - 8), hi = min((int)gridDim.x - 1, bid + 8);
    int ndep = hi - lo + 1;    // <= 17

    float vmask[KOFF];
#pragma unroll
    for (int k = 0; k < KOFF; k++) {
        int nx = x + DXc[k], ny = y + DYc[k], nz = z + DZc[k];
        bool ok = ((unsigned)nx < 64u) & ((unsigned)ny < 64u) &
                  ((unsigned)nz < 64u);
        vmask[k] = ok ? 1.0f : 0.0f;
    }

    float w[KOFF];
#pragma unroll
    for (int k = 0; k < KOFF; k++) w[k] = wpk[k * N_TOTAL + j];

    const float decay = expf(-1.0f / 20.0f);
    float vmem = -65.0f;
    float o1 = 0.0f;   // out_{t-1}[j]
    float o2 = 0.0f;   // out_{t-2}[j]
    float xv = __builtin_nontemporal_load(xext + j);   // slice t=0

    for (int t = 0; t < T; t++) {
        float* pb = (t & 1) ? pb0 : pb1;   // buf[(t-1)&1]
        float* pw = (t & 1) ? pb1 : pb0;   // buf[t&1]
        const float* sr = sout[1 - (t & 1)];   // LDS out_{t-1}
        float* sw = sout[t & 1];               // LDS out_t

        float syn = 0.0f;
        if (t >= 1) {
            float r[NGRP];
            // ---- pre-wait: in-block LDS gathers (sr stable since the
            //      step t-1 publish barrier; sw is the other buffer) ----
#pragma unroll
            for (int g = 0; g < NGRP; g++) {
                float rv = 0.0f;
                if (GDXc[g] == 0) {
                    int ly = lrow + GDYc[g];
                    if ((unsigned)ly < 16u)
                        rv = sr[tid + GDYc[g] * 64];   // ds_read
                }
                r[g] = rv;
            }

            // ---- wait: neighborhood B-8..B+8 completed step t-1 ----
            if (tid < ndep) {
                const unsigned* cp = ctr + (size_t)(lo + tid) * CPAD;
                while (__hip_atomic_load(cp, __ATOMIC_RELAXED,
                                         __HIP_MEMORY_SCOPE_AGENT) <
                       (unsigned)t)
                    __builtin_amdgcn_s_sleep(1);
            }
            __syncthreads();

            // ---- post-wait: remote gathers (cross-block dy, all dx) ----
#pragma unroll
            for (int g = 0; g < NGRP; g++) {
                int dxg = GDXc[g], dyg = GDYc[g];
                if (dxg == 0) {
                    int ly = lrow + dyg;
                    if ((unsigned)ly >= 16u) {
                        int ny = y + dyg;
                        if ((unsigned)ny < 64u)
                            r[g] = __hip_atomic_load(pb + j + GDLc[g],
                                                     __ATOMIC_RELAXED,
                                                     __HIP_MEMORY_SCOPE_AGENT);
                    }
                } else {
                    int nx = x + dxg, ny = y + dyg;
                    if (((unsigned)nx < 64u) & ((unsigned)ny < 64u))
                        r[g] = __hip_atomic_load(pb + j + GDLc[g],
                                                 __ATOMIC_RELAXED,
                                                 __HIP_MEMORY_SCOPE_AGENT);
                }
            }

            if (t >= 2) {
                float h1 = 0.01f * o2;
                float h2 = 0.005f * o2;
#pragma unroll
                for (int k = 0; k < KOFF; k++) {
                    int g = GIDc[k], dz = DZc[k];
                    float src = (g < 0) ? o1 : r[g];
                    float praw = (dz == 0) ? src : __shfl(src, lane + dz, 64);
                    float p = praw * vmask[k];
                    float a = h1 * p;                 // == (0.01f*o2)*p
                    float b = h2 * (1.0f - p);        // == (0.005f*o2)*(1-p)
                    float c = 1e-5f * w[k];
                    float dw = (a - b) - c;
                    w[k] = fminf(fmaxf(w[k] + dw, 0.0f), 1.0f);
                    float m = w[k] * p;   // contract(off): mul then add
                    syn = syn + m;        // k-ascending == segment_sum order
                }
            } else {   // t == 1: syn with stored w, no plasticity yet
#pragma unroll
                for (int k = 0; k < KOFF; k++) {
                    int g = GIDc[k], dz = DZc[k];
                    float src = (g < 0) ? o1 : r[g];
                    float praw = (dz == 0) ? src : __shfl(src, lane + dz, 64);
                    float p = praw * vmask[k];
                    float m = w[k] * p;
                    syn = syn + m;
                }
            }
        }
        // t == 0: prev == 0 -> syn stays 0, no buffer read (poisoned ws ok).

        float I = syn + xv;
        float vn = (vmem * decay) + (I * (1.0f - decay));
        float spike = (vn >= -50.0f) ? 1.0f : 0.0f;
        float inhib = (vn <= -70.0f) ? 1.0f : 0.0f;
        float sg = 1.0f / (1.0f + expf(-((vn - (-60.0f)) * 0.5f)));
        float o = spike + ((1.0f - spike) * (1.0f - inhib)) * sg;
        vmem = (vn * (1.0f - spike)) + (spike * (-65.0f));
        __hip_atomic_store(pw + j, o, __ATOMIC_RELAXED,
                           __HIP_MEMORY_SCOPE_AGENT);
        sw[tid] = o;   // LDS copy (write buffer != read buffer: no WAR race)
        o2 = o1;
        o1 = o;

        // ---- publish: drain data store, then bump own slot (RMW) ----
        __syncthreads();   // vmcnt(0)+lgkmcnt drain: pw & LDS visible
        if (tid == 0)
            __hip_atomic_fetch_add(ctr + (size_t)bid * CPAD, 1u,
                                   __ATOMIC_RELAXED,
                                   __HIP_MEMORY_SCOPE_AGENT);

        // ---- post-publish streaming (latency hides under next wait) ----
        __builtin_nontemporal_store(spike, spk + (size_t)t * N_TOTAL + j);
        int tn = (t + 1 < T) ? (t + 1) : t;
        xv = __builtin_nontemporal_load(xext + (size_t)tn * N_TOTAL + j);
    }
}

extern "C" void kernel_launch(void* const* d_in, const int* in_sizes, int n_in,
                              void* d_out, int out_size, void* d_ws, size_t ws_size,
                              hipStream_t stream) {
    const float* xext = (const float*)d_in[0];
    const float* ev   = (const float*)d_in[1];
    float* spk = (float*)d_out;

    int T = in_sizes[0] / N_TOTAL;   // 50

    // Workspace: W0 (24N) | P0 | P1 | ctr[256*CPAD]  ~= 27.3 MB.
    float* W0 = (float*)d_ws;
    float* P0 = W0 + (size_t)N_TOTAL * KOFF;
    float* P1 = P0 + N_TOTAL;
    unsigned* ctr = (unsigned*)(P1 + N_TOTAL);

    pack_w_kernel<<<N_TOTAL / 256, 256, 0, stream>>>(ev, W0, ctr);

    // Single path, capture-safe: plain launch of the persistent kernel.
    // 256 blocks x 1024 threads, __launch_bounds__(1024,1) -> VGPR<=128 ->
    // 1 block/CU guaranteed schedulable; 256 blocks on 256 CUs co-resident.
    sim_kernel<<<N_TOTAL / 1024, 1024, 0, stream>>>(xext, W0, P0, P1, spk,
                                                    ctr, T);
}